// Round 4
// baseline (280.097 us; speedup 1.0000x reference)
//
#include <hip/hip_runtime.h>
#include <math.h>

#define NB 24
#define DM 128
#define NH 8
#define DK 16
#define LL 512
#define HB (NH * NB)   // 192

// ---------------------------------------------------------------------------
// Workspace layout (floats):
//   QV   [HB][LL][32]      q(*0.25) = [0:16], v = [16:32]   3,145,728 floats
//   K    [HB][DK][LL]                                       1,572,864
//   part [HB][4][18][LL]   fields: 0=mx 1=sm 2+v=acc        7,077,888
//   head [NB][DM][LL]                                       1,572,864
// total 13,369,344 floats = 53.5 MB
// ---------------------------------------------------------------------------
#define QV_OFF   0
#define K_OFF    3145728
#define PART_OFF 4718592
#define HEAD_OFF 11796480

// ---------------------------------------------------------------------------
// Kernel 1: QKV projection. 768 blocks = (hb, l-chunk of 128) x 128 threads.
// One l-column per thread, ALL 48 outputs (q,k,v x 16). W offset depends only
// on blockIdx -> provably wave-uniform -> true s_load (the round-3 version
// derived the k-group from tid>>7, which forced 24 vector loads per iter and
// left the kernel VMEM-issue-bound at VALUBusy 22%).
// Q is pre-scaled by 1/sqrt(DK) = 0.25 here (used only in scores).
// ---------------------------------------------------------------------------
__global__ __launch_bounds__(128)
void qkv_proj(const float* __restrict__ x,
              const float* __restrict__ Wq,
              const float* __restrict__ Wk,
              const float* __restrict__ Wv,
              float* __restrict__ qvbuf,
              float* __restrict__ kbuf)
{
    const int hb = blockIdx.x >> 2;
    const int lc = blockIdx.x & 3;
    const int l  = lc * 128 + threadIdx.x;
    const int b  = hb % NB;

    const float* __restrict__ xb = x + (size_t)b * DM * LL + l;
    const size_t woff = (size_t)hb * DK * DM;       // blockIdx-only -> uniform
    const float* __restrict__ wq = Wq + woff;
    const float* __restrict__ wk = Wk + woff;
    const float* __restrict__ wv = Wv + woff;

    float aq[DK], ak[DK], av[DK];
    #pragma unroll
    for (int k = 0; k < DK; ++k) { aq[k] = 0.f; ak[k] = 0.f; av[k] = 0.f; }

    #pragma unroll 4
    for (int d = 0; d < DM; ++d) {
        const float xv = xb[(size_t)d * LL];        // coalesced, 1 VMEM/iter
        #pragma unroll
        for (int k = 0; k < DK; ++k) {              // s_load-sourced FMAs
            aq[k] = fmaf(wq[k * DM + d], xv, aq[k]);
            ak[k] = fmaf(wk[k * DM + d], xv, ak[k]);
            av[k] = fmaf(wv[k * DM + d], xv, av[k]);
        }
    }

    // Q (scaled), V -> interleaved row layout [hb][l][32]
    float* __restrict__ qvrow = qvbuf + ((size_t)hb * LL + l) * 32;
    #pragma unroll
    for (int c = 0; c < 4; ++c) {
        *reinterpret_cast<float4*>(qvrow + 4 * c) =
            make_float4(0.25f * aq[4*c], 0.25f * aq[4*c+1],
                        0.25f * aq[4*c+2], 0.25f * aq[4*c+3]);
        *reinterpret_cast<float4*>(qvrow + 16 + 4 * c) =
            make_float4(av[4*c], av[4*c+1], av[4*c+2], av[4*c+3]);
    }

    // K -> [hb][k][l] (coalesced along l)
    float* __restrict__ kout = kbuf + (size_t)hb * DK * LL + l;
    #pragma unroll
    for (int k = 0; k < DK; ++k)
        kout[(size_t)k * LL] = ak[k];
}

// ---------------------------------------------------------------------------
// Kernel 2: partial attention. 768 blocks = (hb, l-chunk of 128 rows) x 128
// threads, FOUR output columns per thread (m = tid + 128c). Per row-iter:
// 8 ds_read_b128 + 128 FMA + 4 exp -> ~80% FMA issue fraction (round-3's
// 2-col version measured 39 TF effective at VALUBusy 69%).
// ---------------------------------------------------------------------------
__global__ __launch_bounds__(128)
void attn_part(const float* __restrict__ qvbuf,
               const float* __restrict__ kbuf,
               float* __restrict__ part)
{
    __shared__ __align__(16) float4 QVs[128][8];   // 16 KB

    const int hb  = blockIdx.x >> 2;
    const int lc  = blockIdx.x & 3;
    const int tid = threadIdx.x;

    // stage 128 rows x 32 floats (1024 float4s), fully coalesced
    const float4* __restrict__ src =
        reinterpret_cast<const float4*>(qvbuf + ((size_t)hb * LL + lc * 128) * 32);
    #pragma unroll
    for (int i = tid; i < 1024; i += 128)
        QVs[i >> 3][i & 7] = src[i];

    // K columns for m = tid + 128c (Q already carries the 0.25 scale)
    float kv[4][DK];
    const float* __restrict__ kb = kbuf + (size_t)hb * DK * LL;
    #pragma unroll
    for (int c = 0; c < 4; ++c)
        #pragma unroll
        for (int k = 0; k < DK; ++k)
            kv[c][k] = kb[(size_t)k * LL + tid + 128 * c];
    __syncthreads();

    float mx[4], sm[4], acc[4][DK];
    #pragma unroll
    for (int c = 0; c < 4; ++c) {
        mx[c] = -1e30f; sm[c] = 0.f;
        #pragma unroll
        for (int v = 0; v < DK; ++v) acc[c][v] = 0.f;
    }

    for (int l = 0; l < 128; ++l) {
        float qr[16], vr[16];
        #pragma unroll
        for (int c = 0; c < 4; ++c) {              // broadcast ds_read_b128 x8
            float4 t = QVs[l][c];
            qr[4*c] = t.x; qr[4*c+1] = t.y; qr[4*c+2] = t.z; qr[4*c+3] = t.w;
            float4 u = QVs[l][4 + c];
            vr[4*c] = u.x; vr[4*c+1] = u.y; vr[4*c+2] = u.z; vr[4*c+3] = u.w;
        }
        float s[4];
        #pragma unroll
        for (int c = 0; c < 4; ++c) {
            float sa = 0.f, sb = 0.f;
            #pragma unroll
            for (int k = 0; k < 8; ++k) {
                sa = fmaf(qr[k],     kv[c][k],     sa);
                sb = fmaf(qr[k + 8], kv[c][k + 8], sb);
            }
            s[c] = sa + sb;
        }
        #pragma unroll
        for (int c = 0; c < 4; ++c) {
            if (s[c] > mx[c]) {                    // rare after warm-up
                const float sc = __expf(mx[c] - s[c]);
                sm[c] *= sc;
                #pragma unroll
                for (int v = 0; v < DK; ++v) acc[c][v] *= sc;
                mx[c] = s[c];
            }
            const float p = __expf(s[c] - mx[c]);
            sm[c] += p;
            #pragma unroll
            for (int v = 0; v < DK; ++v)
                acc[c][v] = fmaf(vr[v], p, acc[c][v]);
        }
    }

    // partials: [hb][lc][field][m], coalesced along m
    float* __restrict__ pb = part + ((size_t)(hb * 4 + lc) * 18) * LL;
    #pragma unroll
    for (int c = 0; c < 4; ++c) {
        const int m = tid + 128 * c;
        pb[m] = mx[c];
        pb[LL + m] = sm[c];
        #pragma unroll
        for (int v = 0; v < DK; ++v)
            pb[(size_t)(2 + v) * LL + m] = acc[c][v];
    }
}

// ---------------------------------------------------------------------------
// Kernel 3: merge the 4 l-chunk partials, normalize, write head[b][hk][m].
// 384 blocks = (hb, m-half). All reads/writes coalesced along m.
// ---------------------------------------------------------------------------
__global__ __launch_bounds__(256)
void merge_heads(const float* __restrict__ part,
                 float* __restrict__ head)
{
    const int hb = blockIdx.x >> 1;
    const int m = (blockIdx.x & 1) * 256 + threadIdx.x;
    const float* __restrict__ pb = part + (size_t)hb * 4 * 18 * LL + m;

    float mx[4], sm[4];
    #pragma unroll
    for (int c = 0; c < 4; ++c) {
        mx[c] = pb[(size_t)(c * 18) * LL];
        sm[c] = pb[(size_t)(c * 18 + 1) * LL];
    }
    float M = fmaxf(fmaxf(mx[0], mx[1]), fmaxf(mx[2], mx[3]));
    float e[4], S = 0.f;
    #pragma unroll
    for (int c = 0; c < 4; ++c) { e[c] = __expf(mx[c] - M); S = fmaf(sm[c], e[c], S); }
    const float inv = 1.f / S;

    const int h = hb / NB, b = hb % NB;
    float* __restrict__ ho = head + ((size_t)b * DM + h * DK) * LL + m;
    #pragma unroll
    for (int v = 0; v < DK; ++v) {
        float a = 0.f;
        #pragma unroll
        for (int c = 0; c < 4; ++c)
            a = fmaf(pb[(size_t)(c * 18 + 2 + v) * LL], e[c], a);
        ho[(size_t)v * LL] = a * inv;
    }
}

// ---------------------------------------------------------------------------
// Kernel 4: out[b] = Wo[b] @ head[b]. 384 blocks = (b, row-chunk 16, col-half)
// x 256 threads, one col + 16 rows per thread. Row offset depends only on
// blockIdx -> Wo reads are true s_loads (round-3 used tid>>6 -> vector loads).
// ---------------------------------------------------------------------------
__global__ __launch_bounds__(256)
void out_proj(const float* __restrict__ Wo,
              const float* __restrict__ head,
              float* __restrict__ out)
{
    const int blk  = blockIdx.x;
    const int b    = blk >> 4;
    const int rc   = (blk >> 1) & 7;
    const int cc   = blk & 1;
    const int col  = cc * 256 + threadIdx.x;
    const int row0 = rc * 16;                      // blockIdx-only -> uniform

    const float* __restrict__ wo = Wo + (size_t)b * DM * DM + (size_t)row0 * DM;
    const float* __restrict__ hd = head + (size_t)b * DM * LL + col;

    float acc[16];
    #pragma unroll
    for (int i = 0; i < 16; ++i) acc[i] = 0.f;

    #pragma unroll 4
    for (int d = 0; d < DM; ++d) {
        const float hv = hd[(size_t)d * LL];       // coalesced, 1 VMEM/iter
        #pragma unroll
        for (int i = 0; i < 16; ++i)               // s_load-sourced FMAs
            acc[i] = fmaf(wo[i * DM + d], hv, acc[i]);
    }

    float* __restrict__ ob = out + (size_t)b * DM * LL + (size_t)row0 * LL + col;
    #pragma unroll
    for (int i = 0; i < 16; ++i)
        ob[(size_t)i * LL] = acc[i];
}

extern "C" void kernel_launch(void* const* d_in, const int* in_sizes, int n_in,
                              void* d_out, int out_size, void* d_ws, size_t ws_size,
                              hipStream_t stream) {
    const float* x  = (const float*)d_in[0];
    const float* Wq = (const float*)d_in[1];
    const float* Wk = (const float*)d_in[2];
    const float* Wv = (const float*)d_in[3];
    const float* Wo = (const float*)d_in[4];
    float* out = (float*)d_out;

    float* ws   = (float*)d_ws;
    float* qv   = ws + QV_OFF;
    float* kbuf = ws + K_OFF;
    float* part = ws + PART_OFF;
    float* head = ws + HEAD_OFF;

    qkv_proj   <<<HB * 4, 128, 0, stream>>>(x, Wq, Wk, Wv, qv, kbuf);
    attn_part  <<<HB * 4, 128, 0, stream>>>(qv, kbuf, part);
    merge_heads<<<HB * 2, 256, 0, stream>>>(part, head);
    out_proj   <<<NB * 16, 256, 0, stream>>>(Wo, head, out);
}

// Round 5
// 197.818 us; speedup vs baseline: 1.4159x; 1.4159x over previous
//
#include <hip/hip_runtime.h>
#include <math.h>

#define NB 24
#define DM 128
#define NH 8
#define DK 16
#define LL 512
#define HB (NH * NB)   // 192

// ---------------------------------------------------------------------------
// Workspace layout (floats) — identical footprint to the validated round-3
// layout (53.5 MB total):
//   QV   [HB][LL][32]      q(*0.25) = [0:16], v = [16:32]   3,145,728
//   K    [HB][DK][LL]                                       1,572,864
//   part [HB][4][18][LL]   fields: 0=mx 1=sm 2+v=acc        7,077,888
//   head [NB][DM][LL]                                       1,572,864
// ---------------------------------------------------------------------------
#define QV_OFF   0
#define K_OFF    3145728
#define PART_OFF 4718592
#define HEAD_OFF 11796480

// ---------------------------------------------------------------------------
// Kernel 1: QKV projection, split by matrix. 1152 blocks = (hb, lc of 256,
// mat in {q,k,v}) x 256 threads -> 18 waves/CU. Per thread: one l-column,
// 16 outputs of ONE matrix. Per unroll-4 d-chunk: 16 s_load_dwordx4 =
// 64 SGPRs live (fits — round 4's 48-row version needed ~192 and thrashed),
// 4 coalesced vmem, 64 FMA.
// ---------------------------------------------------------------------------
__global__ __launch_bounds__(256)
void qkv_proj(const float* __restrict__ x,
              const float* __restrict__ Wq,
              const float* __restrict__ Wk,
              const float* __restrict__ Wv,
              float* __restrict__ qvbuf,
              float* __restrict__ kbuf)
{
    const int blk = blockIdx.x;
    const int hb  = blk / 6;
    const int rem = blk - hb * 6;
    const int lc  = rem / 3;          // 0..1
    const int mat = rem - lc * 3;     // 0=Q 1=K 2=V
    const int l   = lc * 256 + threadIdx.x;
    const int b   = hb % NB;

    const float* __restrict__ xb = x + (size_t)b * DM * LL + l;
    const float* __restrict__ W =
        (mat == 0 ? Wq : (mat == 1 ? Wk : Wv)) + (size_t)hb * DK * DM;

    float acc[DK];
    #pragma unroll
    for (int k = 0; k < DK; ++k) acc[k] = 0.f;

    #pragma unroll 4
    for (int d = 0; d < DM; ++d) {
        const float xv = xb[(size_t)d * LL];       // coalesced, 1 VMEM/d
        #pragma unroll
        for (int k = 0; k < DK; ++k)               // W -> s_load (uniform)
            acc[k] = fmaf(W[k * DM + d], xv, acc[k]);
    }

    if (mat == 0) {                                // Q * 0.25 -> [hb][l][0:16]
        float* __restrict__ qvrow = qvbuf + ((size_t)hb * LL + l) * 32;
        #pragma unroll
        for (int c = 0; c < 4; ++c)
            *reinterpret_cast<float4*>(qvrow + 4 * c) =
                make_float4(0.25f * acc[4*c],   0.25f * acc[4*c+1],
                            0.25f * acc[4*c+2], 0.25f * acc[4*c+3]);
    } else if (mat == 2) {                         // V -> [hb][l][16:32]
        float* __restrict__ qvrow = qvbuf + ((size_t)hb * LL + l) * 32 + 16;
        #pragma unroll
        for (int c = 0; c < 4; ++c)
            *reinterpret_cast<float4*>(qvrow + 4 * c) =
                make_float4(acc[4*c], acc[4*c+1], acc[4*c+2], acc[4*c+3]);
    } else {                                       // K -> [hb][k][l]
        float* __restrict__ kout = kbuf + (size_t)hb * DK * LL + l;
        #pragma unroll
        for (int k = 0; k < DK; ++k)
            kout[(size_t)k * LL] = acc[k];
    }
}

// ---------------------------------------------------------------------------
// Kernel 2: partial attention, NO LDS. 768 blocks = (hb, l-chunk of 128 rows)
// x 256 threads (2 cols/thread) -> 12 waves/CU. The QV row address depends
// only on blockIdx + loop index -> wave-uniform -> the compiler scalarizes the
// 32 row floats into 2x s_load_dwordx16 on the SCALAR pipe. Round 3's LDS
// version spent ~96 LDS-unit cyc/wave-row (8x broadcast ds_read_b128), which
// saturated the per-CU LDS pipe at 12 waves/CU; the scalar pipe rides free.
// Per row-iter: 64 FMA + 2 exp + ~10 misc VALU, 0 LDS, 0 VMEM.
// ---------------------------------------------------------------------------
__global__ __launch_bounds__(256)
void attn_part(const float* __restrict__ qvbuf,
               const float* __restrict__ kbuf,
               float* __restrict__ part)
{
    const int hb  = blockIdx.x >> 2;
    const int lc  = blockIdx.x & 3;
    const int tid = threadIdx.x;
    const int m0 = tid, m1 = tid + 256;

    // K columns (per-lane, VGPR). Q already carries the 0.25 scale.
    float kv0[DK], kv1[DK];
    const float* __restrict__ kb = kbuf + (size_t)hb * DK * LL;
    #pragma unroll
    for (int k = 0; k < DK; ++k) {
        kv0[k] = kb[(size_t)k * LL + m0];
        kv1[k] = kb[(size_t)k * LL + m1];
    }

    const float* __restrict__ rowp = qvbuf + ((size_t)hb * LL + lc * 128) * 32;

    float mx0 = -1e30f, mx1 = -1e30f, sm0 = 0.f, sm1 = 0.f;
    float acc0[DK], acc1[DK];
    #pragma unroll
    for (int v = 0; v < DK; ++v) { acc0[v] = 0.f; acc1[v] = 0.f; }

    #pragma unroll 2
    for (int r = 0; r < 128; ++r) {
        const float* __restrict__ rp = rowp + r * 32;   // uniform -> s_load
        float qr[16], vr[16];
        #pragma unroll
        for (int j = 0; j < 16; ++j) { qr[j] = rp[j]; vr[j] = rp[16 + j]; }

        float s0a = 0.f, s0b = 0.f, s1a = 0.f, s1b = 0.f;
        #pragma unroll
        for (int k = 0; k < 8; ++k) {
            s0a = fmaf(qr[k],     kv0[k],     s0a);
            s0b = fmaf(qr[k + 8], kv0[k + 8], s0b);
            s1a = fmaf(qr[k],     kv1[k],     s1a);
            s1b = fmaf(qr[k + 8], kv1[k + 8], s1b);
        }
        const float s0 = s0a + s0b;
        const float s1 = s1a + s1b;

        if (s0 > mx0) {
            const float sc = __expf(mx0 - s0);
            sm0 *= sc;
            #pragma unroll
            for (int v = 0; v < DK; ++v) acc0[v] *= sc;
            mx0 = s0;
        }
        if (s1 > mx1) {
            const float sc = __expf(mx1 - s1);
            sm1 *= sc;
            #pragma unroll
            for (int v = 0; v < DK; ++v) acc1[v] *= sc;
            mx1 = s1;
        }
        const float p0 = __expf(s0 - mx0);
        const float p1 = __expf(s1 - mx1);
        sm0 += p0; sm1 += p1;
        #pragma unroll
        for (int v = 0; v < DK; ++v) {
            acc0[v] = fmaf(vr[v], p0, acc0[v]);
            acc1[v] = fmaf(vr[v], p1, acc1[v]);
        }
    }

    // partials: [hb][lc][field][m], coalesced along m
    float* __restrict__ pb = part + ((size_t)(hb * 4 + lc) * 18) * LL;
    pb[m0] = mx0;             pb[m1] = mx1;
    pb[LL + m0] = sm0;        pb[LL + m1] = sm1;
    #pragma unroll
    for (int v = 0; v < DK; ++v) {
        pb[(size_t)(2 + v) * LL + m0] = acc0[v];
        pb[(size_t)(2 + v) * LL + m1] = acc1[v];
    }
}

// ---------------------------------------------------------------------------
// Kernel 3: merge the 4 l-chunk partials, normalize, write head[b][hk][m].
// 1536 blocks = (hb, m-half, v-quad) -> 24 waves/CU; each thread merges
// 4 of the 16 v-rows for one m. All reads/writes coalesced along m.
// ---------------------------------------------------------------------------
__global__ __launch_bounds__(256)
void merge_heads(const float* __restrict__ part,
                 float* __restrict__ head)
{
    const int blk = blockIdx.x;
    const int hb  = blk >> 3;
    const int mh  = (blk >> 2) & 1;
    const int vq  = blk & 3;
    const int m   = mh * 256 + threadIdx.x;
    const int v0  = vq * 4;

    const float* __restrict__ pb = part + (size_t)hb * 4 * 18 * LL + m;

    float mx[4], sm[4];
    #pragma unroll
    for (int c = 0; c < 4; ++c) {
        mx[c] = pb[(size_t)(c * 18) * LL];
        sm[c] = pb[(size_t)(c * 18 + 1) * LL];
    }
    float M = fmaxf(fmaxf(mx[0], mx[1]), fmaxf(mx[2], mx[3]));
    float e[4], S = 0.f;
    #pragma unroll
    for (int c = 0; c < 4; ++c) { e[c] = __expf(mx[c] - M); S = fmaf(sm[c], e[c], S); }
    const float inv = 1.f / S;

    const int h = hb / NB, b = hb % NB;
    float* __restrict__ ho = head + ((size_t)b * DM + h * DK + v0) * LL + m;
    #pragma unroll
    for (int v = 0; v < 4; ++v) {
        float a = 0.f;
        #pragma unroll
        for (int c = 0; c < 4; ++c)
            a = fmaf(pb[(size_t)(c * 18 + 2 + v0 + v) * LL], e[c], a);
        ho[(size_t)v * LL] = a * inv;
    }
}

// ---------------------------------------------------------------------------
// Kernel 4: out[b] = Wo[b] @ head[b]. 768 blocks = (b, row-chunk of 8,
// col-half) x 256 threads -> 12 waves/CU. 8 rows/thread: per unroll-4 chunk
// 8 s_load_dwordx4 = 32 SGPRs live, 4 vmem, 32 FMA.
// ---------------------------------------------------------------------------
__global__ __launch_bounds__(256)
void out_proj(const float* __restrict__ Wo,
              const float* __restrict__ head,
              float* __restrict__ out)
{
    const int blk  = blockIdx.x;
    const int b    = blk >> 5;
    const int rc   = (blk >> 1) & 15;
    const int cc   = blk & 1;
    const int col  = cc * 256 + threadIdx.x;
    const int row0 = rc * 8;                       // blockIdx-only -> uniform

    const float* __restrict__ wo = Wo + (size_t)b * DM * DM + (size_t)row0 * DM;
    const float* __restrict__ hd = head + (size_t)b * DM * LL + col;

    float acc[8];
    #pragma unroll
    for (int i = 0; i < 8; ++i) acc[i] = 0.f;

    #pragma unroll 4
    for (int d = 0; d < DM; ++d) {
        const float hv = hd[(size_t)d * LL];       // coalesced, 1 VMEM/d
        #pragma unroll
        for (int i = 0; i < 8; ++i)                // Wo -> s_load (uniform)
            acc[i] = fmaf(wo[i * DM + d], hv, acc[i]);
    }

    float* __restrict__ ob = out + (size_t)b * DM * LL + (size_t)row0 * LL + col;
    #pragma unroll
    for (int i = 0; i < 8; ++i)
        ob[(size_t)i * LL] = acc[i];
}

extern "C" void kernel_launch(void* const* d_in, const int* in_sizes, int n_in,
                              void* d_out, int out_size, void* d_ws, size_t ws_size,
                              hipStream_t stream) {
    const float* x  = (const float*)d_in[0];
    const float* Wq = (const float*)d_in[1];
    const float* Wk = (const float*)d_in[2];
    const float* Wv = (const float*)d_in[3];
    const float* Wo = (const float*)d_in[4];
    float* out = (float*)d_out;

    float* ws   = (float*)d_ws;
    float* qv   = ws + QV_OFF;
    float* kbuf = ws + K_OFF;
    float* part = ws + PART_OFF;
    float* head = ws + HEAD_OFF;

    qkv_proj   <<<HB * 6, 256, 0, stream>>>(x, Wq, Wk, Wv, qv, kbuf);
    attn_part  <<<HB * 4, 256, 0, stream>>>(qv, kbuf, part);
    merge_heads<<<HB * 8, 256, 0, stream>>>(part, head);
    out_proj   <<<NB * 32, 256, 0, stream>>>(Wo, head, out);
}

// Round 6
// 193.741 us; speedup vs baseline: 1.4457x; 1.0210x over previous
//
#include <hip/hip_runtime.h>
#include <math.h>

#define NB 24
#define DM 128
#define NH 8
#define DK 16
#define LL 512
#define HB (NH * NB)   // 192

// ---------------------------------------------------------------------------
// Workspace layout (floats) — unchanged from round 3/5 (53.5 MB total):
//   QV   [HB][LL][32]      q(*0.25) = [0:16], v = [16:32]   3,145,728
//   K    [HB][DK][LL]                                       1,572,864
//   part [HB][4][18][LL]   fields: 0=mx 1=sm 2+v=acc        7,077,888
//   head [NB][DM][LL]                                       1,572,864
// ---------------------------------------------------------------------------
#define QV_OFF   0
#define K_OFF    3145728
#define PART_OFF 4718592
#define HEAD_OFF 11796480

#define E32 1.2664166e-14f   // expf(-32)

// ---------------------------------------------------------------------------
// Kernel 1: QKV projection. 576 blocks = (hb, mat) x 256 threads, TWO
// l-columns per thread (tid, tid+256). Per d-iter: 2 coalesced vmem + 32 FMA
// fed by 16 wave-uniform W values (s_load) -> half the scalar-load pressure
// per FMA of the round-5 version.
// ---------------------------------------------------------------------------
__global__ __launch_bounds__(256)
void qkv_proj(const float* __restrict__ x,
              const float* __restrict__ Wq,
              const float* __restrict__ Wk,
              const float* __restrict__ Wv,
              float* __restrict__ qvbuf,
              float* __restrict__ kbuf)
{
    const int blk = blockIdx.x;
    const int hb  = blk / 3;
    const int mat = blk - hb * 3;     // 0=Q 1=K 2=V
    const int l0  = threadIdx.x;
    const int l1  = threadIdx.x + 256;
    const int b   = hb % NB;

    const float* __restrict__ xb = x + (size_t)b * DM * LL;
    const float* __restrict__ W =
        (mat == 0 ? Wq : (mat == 1 ? Wk : Wv)) + (size_t)hb * DK * DM;

    float a0[DK], a1[DK];
    #pragma unroll
    for (int k = 0; k < DK; ++k) { a0[k] = 0.f; a1[k] = 0.f; }

    #pragma unroll 4
    for (int d = 0; d < DM; ++d) {
        const float x0 = xb[(size_t)d * LL + l0];  // coalesced
        const float x1 = xb[(size_t)d * LL + l1];  // coalesced
        #pragma unroll
        for (int k = 0; k < DK; ++k) {             // W -> s_load (uniform)
            const float w = W[k * DM + d];
            a0[k] = fmaf(w, x0, a0[k]);
            a1[k] = fmaf(w, x1, a1[k]);
        }
    }

    if (mat == 0) {                                // Q * 0.25 -> [hb][l][0:16]
        float* __restrict__ r0 = qvbuf + ((size_t)hb * LL + l0) * 32;
        float* __restrict__ r1 = qvbuf + ((size_t)hb * LL + l1) * 32;
        #pragma unroll
        for (int c = 0; c < 4; ++c) {
            *reinterpret_cast<float4*>(r0 + 4 * c) =
                make_float4(0.25f * a0[4*c],   0.25f * a0[4*c+1],
                            0.25f * a0[4*c+2], 0.25f * a0[4*c+3]);
            *reinterpret_cast<float4*>(r1 + 4 * c) =
                make_float4(0.25f * a1[4*c],   0.25f * a1[4*c+1],
                            0.25f * a1[4*c+2], 0.25f * a1[4*c+3]);
        }
    } else if (mat == 2) {                         // V -> [hb][l][16:32]
        float* __restrict__ r0 = qvbuf + ((size_t)hb * LL + l0) * 32 + 16;
        float* __restrict__ r1 = qvbuf + ((size_t)hb * LL + l1) * 32 + 16;
        #pragma unroll
        for (int c = 0; c < 4; ++c) {
            *reinterpret_cast<float4*>(r0 + 4 * c) =
                make_float4(a0[4*c], a0[4*c+1], a0[4*c+2], a0[4*c+3]);
            *reinterpret_cast<float4*>(r1 + 4 * c) =
                make_float4(a1[4*c], a1[4*c+1], a1[4*c+2], a1[4*c+3]);
        }
    } else {                                       // K -> [hb][k][l]
        float* __restrict__ kout = kbuf + (size_t)hb * DK * LL;
        #pragma unroll
        for (int k = 0; k < DK; ++k) {
            kout[(size_t)k * LL + l0] = a0[k];
            kout[(size_t)k * LL + l1] = a1[k];
        }
    }
}

// ---------------------------------------------------------------------------
// Kernel 2: partial attention. 768 blocks = (hb, l-chunk of 128 rows) x 256
// threads, 2 cols/thread. QV rows staged in 16 KB LDS, read as broadcast
// ds_read_b128 (0 conflicts measured in round 3).
//
// HYSTERESIS online softmax (exact): the offset bar is set 32 above the
// triggering score, so a rescale only fires when a score beats the bar by
// >32 — a handful of wave-level body executions per 128 rows instead of
// round 5's ~128 (the per-lane `s>mx` union across 128 cols/wave fired every
// iter, costing ~270 VALU cyc/iter; measured VALUBusy 51% at 530 cyc/iter).
// All weights stay >= e^-64 (fp32 min normal 1e-38): arithmetic is exact,
// and merge_heads already handles arbitrary per-chunk offsets.
// Common path per col per row: 1 sub + 1 cmp + 1 exp + 1 add + 16 FMA.
// ---------------------------------------------------------------------------
__global__ __launch_bounds__(256)
void attn_part(const float* __restrict__ qvbuf,
               const float* __restrict__ kbuf,
               float* __restrict__ part)
{
    __shared__ __align__(16) float4 QVs[128][8];   // 16 KB

    const int hb  = blockIdx.x >> 2;
    const int lc  = blockIdx.x & 3;
    const int tid = threadIdx.x;
    const int m0 = tid, m1 = tid + 256;

    // stage 128 rows x 32 floats (1024 float4s), fully coalesced
    const float4* __restrict__ src =
        reinterpret_cast<const float4*>(qvbuf + ((size_t)hb * LL + lc * 128) * 32);
    #pragma unroll
    for (int i = tid; i < 1024; i += 256)
        QVs[i >> 3][i & 7] = src[i];

    // K columns (per-lane VGPR; Q already carries the 0.25 scale)
    float kv0[DK], kv1[DK];
    const float* __restrict__ kb = kbuf + (size_t)hb * DK * LL;
    #pragma unroll
    for (int k = 0; k < DK; ++k) {
        kv0[k] = kb[(size_t)k * LL + m0];
        kv1[k] = kb[(size_t)k * LL + m1];
    }
    __syncthreads();

    float mx0 = -1e30f, mx1 = -1e30f, sm0 = 0.f, sm1 = 0.f;
    float acc0[DK], acc1[DK];
    #pragma unroll
    for (int v = 0; v < DK; ++v) { acc0[v] = 0.f; acc1[v] = 0.f; }

    #pragma unroll 2
    for (int r = 0; r < 128; ++r) {
        float qr[16], vr[16];
        #pragma unroll
        for (int c = 0; c < 4; ++c) {              // broadcast ds_read_b128 x8
            float4 t = QVs[r][c];
            qr[4*c] = t.x; qr[4*c+1] = t.y; qr[4*c+2] = t.z; qr[4*c+3] = t.w;
            float4 u = QVs[r][4 + c];
            vr[4*c] = u.x; vr[4*c+1] = u.y; vr[4*c+2] = u.z; vr[4*c+3] = u.w;
        }
        float s0a = 0.f, s0b = 0.f, s1a = 0.f, s1b = 0.f;
        #pragma unroll
        for (int k = 0; k < 8; ++k) {
            s0a = fmaf(qr[k],     kv0[k],     s0a);
            s0b = fmaf(qr[k + 8], kv0[k + 8], s0b);
            s1a = fmaf(qr[k],     kv1[k],     s1a);
            s1b = fmaf(qr[k + 8], kv1[k + 8], s1b);
        }
        const float s0 = s0a + s0b;
        const float s1 = s1a + s1b;

        const float d0 = s0 - mx0;
        if (d0 > 0.f) {                            // rare at wave level
            const float sc = __expf(-32.f - d0);   // old_mx - new_mx
            sm0 = sm0 * sc + E32;                  // this row contributes e^-32
            #pragma unroll
            for (int v = 0; v < DK; ++v)
                acc0[v] = fmaf(acc0[v], sc, E32 * vr[v]);
            mx0 = s0 + 32.f;
        } else {
            const float p = __expf(d0);
            sm0 += p;
            #pragma unroll
            for (int v = 0; v < DK; ++v)
                acc0[v] = fmaf(vr[v], p, acc0[v]);
        }

        const float d1 = s1 - mx1;
        if (d1 > 0.f) {
            const float sc = __expf(-32.f - d1);
            sm1 = sm1 * sc + E32;
            #pragma unroll
            for (int v = 0; v < DK; ++v)
                acc1[v] = fmaf(acc1[v], sc, E32 * vr[v]);
            mx1 = s1 + 32.f;
        } else {
            const float p = __expf(d1);
            sm1 += p;
            #pragma unroll
            for (int v = 0; v < DK; ++v)
                acc1[v] = fmaf(vr[v], p, acc1[v]);
        }
    }

    // partials: [hb][lc][field][m], coalesced along m
    float* __restrict__ pb = part + ((size_t)(hb * 4 + lc) * 18) * LL;
    pb[m0] = mx0;             pb[m1] = mx1;
    pb[LL + m0] = sm0;        pb[LL + m1] = sm1;
    #pragma unroll
    for (int v = 0; v < DK; ++v) {
        pb[(size_t)(2 + v) * LL + m0] = acc0[v];
        pb[(size_t)(2 + v) * LL + m1] = acc1[v];
    }
}

// ---------------------------------------------------------------------------
// Kernel 3: merge the 4 l-chunk partials, normalize, write head[b][hk][m].
// 1536 blocks = (hb, m-half, v-quad) -> 24 waves/CU. Coalesced along m.
// ---------------------------------------------------------------------------
__global__ __launch_bounds__(256)
void merge_heads(const float* __restrict__ part,
                 float* __restrict__ head)
{
    const int blk = blockIdx.x;
    const int hb  = blk >> 3;
    const int mh  = (blk >> 2) & 1;
    const int vq  = blk & 3;
    const int m   = mh * 256 + threadIdx.x;
    const int v0  = vq * 4;

    const float* __restrict__ pb = part + (size_t)hb * 4 * 18 * LL + m;

    float mx[4], sm[4];
    #pragma unroll
    for (int c = 0; c < 4; ++c) {
        mx[c] = pb[(size_t)(c * 18) * LL];
        sm[c] = pb[(size_t)(c * 18 + 1) * LL];
    }
    float M = fmaxf(fmaxf(mx[0], mx[1]), fmaxf(mx[2], mx[3]));
    float e[4], S = 0.f;
    #pragma unroll
    for (int c = 0; c < 4; ++c) { e[c] = __expf(mx[c] - M); S = fmaf(sm[c], e[c], S); }
    const float inv = 1.f / S;

    const int h = hb / NB, b = hb % NB;
    float* __restrict__ ho = head + ((size_t)b * DM + h * DK + v0) * LL + m;
    #pragma unroll
    for (int v = 0; v < 4; ++v) {
        float a = 0.f;
        #pragma unroll
        for (int c = 0; c < 4; ++c)
            a = fmaf(pb[(size_t)(c * 18 + 2 + v0 + v) * LL], e[c], a);
        ho[(size_t)v * LL] = a * inv;
    }
}

// ---------------------------------------------------------------------------
// Kernel 4: out[b] = Wo[b] @ head[b]. 768 blocks = (b, row-chunk of 8,
// col-half) x 256 threads -> 12 waves/CU. Wo -> s_load (uniform rows).
// ---------------------------------------------------------------------------
__global__ __launch_bounds__(256)
void out_proj(const float* __restrict__ Wo,
              const float* __restrict__ head,
              float* __restrict__ out)
{
    const int blk  = blockIdx.x;
    const int b    = blk >> 5;
    const int rc   = (blk >> 1) & 15;
    const int cc   = blk & 1;
    const int col  = cc * 256 + threadIdx.x;
    const int row0 = rc * 8;                       // blockIdx-only -> uniform

    const float* __restrict__ wo = Wo + (size_t)b * DM * DM + (size_t)row0 * DM;
    const float* __restrict__ hd = head + (size_t)b * DM * LL + col;

    float acc[8];
    #pragma unroll
    for (int i = 0; i < 8; ++i) acc[i] = 0.f;

    #pragma unroll 4
    for (int d = 0; d < DM; ++d) {
        const float hv = hd[(size_t)d * LL];       // coalesced, 1 VMEM/d
        #pragma unroll
        for (int i = 0; i < 8; ++i)                // Wo -> s_load (uniform)
            acc[i] = fmaf(wo[i * DM + d], hv, acc[i]);
    }

    float* __restrict__ ob = out + (size_t)b * DM * LL + (size_t)row0 * LL + col;
    #pragma unroll
    for (int i = 0; i < 8; ++i)
        ob[(size_t)i * LL] = acc[i];
}

extern "C" void kernel_launch(void* const* d_in, const int* in_sizes, int n_in,
                              void* d_out, int out_size, void* d_ws, size_t ws_size,
                              hipStream_t stream) {
    const float* x  = (const float*)d_in[0];
    const float* Wq = (const float*)d_in[1];
    const float* Wk = (const float*)d_in[2];
    const float* Wv = (const float*)d_in[3];
    const float* Wo = (const float*)d_in[4];
    float* out = (float*)d_out;

    float* ws   = (float*)d_ws;
    float* qv   = ws + QV_OFF;
    float* kbuf = ws + K_OFF;
    float* part = ws + PART_OFF;
    float* head = ws + HEAD_OFF;

    qkv_proj   <<<HB * 3, 256, 0, stream>>>(x, Wq, Wk, Wv, qv, kbuf);
    attn_part  <<<HB * 4, 256, 0, stream>>>(qv, kbuf, part);
    merge_heads<<<HB * 8, 256, 0, stream>>>(part, head);
    out_proj   <<<NB * 32, 256, 0, stream>>>(Wo, head, out);
}

// Round 9
// 133.257 us; speedup vs baseline: 2.1019x; 1.4539x over previous
//
#include <hip/hip_runtime.h>
#include <math.h>

#define NB 24
#define DM 128
#define NH 8
#define DK 16
#define LL 512
#define HB (NH * NB)   // 192

// ---------------------------------------------------------------------------
// Workspace layout (BYTES), total 22 MB:
//   Qbuf [HB][LL][32] ushort : bf16 split rows, [0:16]=hi(k), [16:32]=lo(k)
//   Kbuf [HB][LL][32] ushort : same, K pre-scaled by 0.25*log2e (softmax in
//                              exp2 domain -> v_exp_f32 is exp2 natively)
//   Vbuf [HB][DK][LL] ushort : plain bf16
//   head [NB][DM][LL] float
// ---------------------------------------------------------------------------
#define QB_OFF   0
#define KB_OFF   6291456
#define VB_OFF   12582912
#define HEAD_OFF 15728640

typedef __attribute__((ext_vector_type(8))) short bf16x8;   // 4 VGPR MFMA A/B
typedef __attribute__((ext_vector_type(4))) float f32x4;    // MFMA C/D
typedef __attribute__((ext_vector_type(4))) int   i32x4;

#define MFMA  __builtin_amdgcn_mfma_f32_16x16x32_bf16
#define EXP2  __builtin_amdgcn_exp2f
#define BPERM __builtin_amdgcn_ds_bpermute

// bf16 rounding (round-half-up), result kept in the high half of a uint
static __device__ __forceinline__ unsigned bfr(float x) {
    return (__float_as_uint(x) + 0x8000u) & 0xffff0000u;
}
// pack two bf16-bits (even elem, odd elem) into one dword, little-endian
static __device__ __forceinline__ unsigned pk2(unsigned e, unsigned o) {
    return (e >> 16) | o;
}

// ---------------------------------------------------------------------------
// Kernel 1: QKV projection (fp32 VALU, round-6 structure) + bf16-split emit.
// 576 blocks = (hb, mat); 2 l-columns/thread; W reads wave-uniform (s_load).
// ---------------------------------------------------------------------------
static __device__ __forceinline__ void store_split_row(
    unsigned short* __restrict__ row, const float* a, float scale)
{
    unsigned hi[16], lo[16];
    #pragma unroll
    for (int k = 0; k < 16; ++k) {
        const float v = a[k] * scale;
        hi[k] = bfr(v);
        lo[k] = bfr(v - __uint_as_float(hi[k]));   // v - hi is exact in fp32
    }
    uint4* r = (uint4*)row;
    uint4 d0 = { pk2(hi[0],hi[1]),  pk2(hi[2],hi[3]),  pk2(hi[4],hi[5]),  pk2(hi[6],hi[7]) };
    uint4 d1 = { pk2(hi[8],hi[9]),  pk2(hi[10],hi[11]),pk2(hi[12],hi[13]),pk2(hi[14],hi[15]) };
    uint4 d2 = { pk2(lo[0],lo[1]),  pk2(lo[2],lo[3]),  pk2(lo[4],lo[5]),  pk2(lo[6],lo[7]) };
    uint4 d3 = { pk2(lo[8],lo[9]),  pk2(lo[10],lo[11]),pk2(lo[12],lo[13]),pk2(lo[14],lo[15]) };
    r[0] = d0; r[1] = d1; r[2] = d2; r[3] = d3;
}

__global__ __launch_bounds__(256)
void qkv_proj(const float* __restrict__ x,
              const float* __restrict__ Wq,
              const float* __restrict__ Wk,
              const float* __restrict__ Wv,
              unsigned short* __restrict__ qb,
              unsigned short* __restrict__ kb,
              unsigned short* __restrict__ vb)
{
    const int blk = blockIdx.x;
    const int hb  = blk / 3;
    const int mat = blk - hb * 3;     // 0=Q 1=K 2=V
    const int l0  = threadIdx.x;
    const int l1  = threadIdx.x + 256;
    const int b   = hb % NB;

    const float* __restrict__ xb = x + (size_t)b * DM * LL;
    const float* __restrict__ W =
        (mat == 0 ? Wq : (mat == 1 ? Wk : Wv)) + (size_t)hb * DK * DM;

    float a0[DK], a1[DK];
    #pragma unroll
    for (int k = 0; k < DK; ++k) { a0[k] = 0.f; a1[k] = 0.f; }

    #pragma unroll 4
    for (int d = 0; d < DM; ++d) {
        const float x0 = xb[(size_t)d * LL + l0];   // coalesced
        const float x1 = xb[(size_t)d * LL + l1];
        #pragma unroll
        for (int k = 0; k < DK; ++k) {              // W -> s_load (uniform)
            const float w = W[k * DM + d];
            a0[k] = fmaf(w, x0, a0[k]);
            a1[k] = fmaf(w, x1, a1[k]);
        }
    }

    if (mat == 2) {                                 // V -> plain bf16 [hb][v][l]
        unsigned short* __restrict__ vo = vb + (size_t)hb * DK * LL;
        #pragma unroll
        for (int k = 0; k < DK; ++k) {
            vo[(size_t)k * LL + l0] = (unsigned short)(bfr(a0[k]) >> 16);
            vo[(size_t)k * LL + l1] = (unsigned short)(bfr(a1[k]) >> 16);
        }
    } else {
        const float scale = (mat == 1) ? (0.25f * 1.44269504f) : 1.0f;
        unsigned short* __restrict__ base =
            (mat == 0 ? qb : kb) + (size_t)hb * LL * 32;
        store_split_row(base + (size_t)l0 * 32, a0, scale);
        store_split_row(base + (size_t)l1 * 32, a1, scale);
    }
}

// ---------------------------------------------------------------------------
// Kernel 2: MFMA flash attention (softmax over l = query axis).
// 768 blocks = (hb, m-chunk of 128) x 4 waves; wave owns 32 m (2 16-tiles).
//
// ROUND-9 FIX: tile-skip threshold was `tm + 32 > bar`, i.e. "include only
// if this tile BEATS the running max" — dropped near-max-weight tiles
// (expected inclusions ~ln(16)≈3 of 16 -> denominator ~5x small, absmax
// ~115-450). With bar = max_tm + 32, relative contribution of a tile is
// exp2(tm - bar + 32); skipping below 2^-32 requires `tm + 64 > bar`.
// ---------------------------------------------------------------------------
static __device__ __forceinline__ void soft_pv(
    const f32x4& s0, const f32x4& s1, float tm, float& bar, float& sm,
    f32x4& O, const bf16x8& aV, int aLo, int aHi, bool up)
{
    const float nb = fmaxf(bar, tm + 32.f);
    const float f  = EXP2(bar - nb);
    bar = nb;
    // p = exp2(s - bar); bf16-rounded bits (sum uses the SAME rounded values)
    const unsigned u0 = bfr(EXP2(s0[0]-nb)), u1 = bfr(EXP2(s0[1]-nb));
    const unsigned u2 = bfr(EXP2(s0[2]-nb)), u3 = bfr(EXP2(s0[3]-nb));
    const unsigned w0 = bfr(EXP2(s1[0]-nb)), w1 = bfr(EXP2(s1[1]-nb));
    const unsigned w2 = bfr(EXP2(s1[2]-nb)), w3 = bfr(EXP2(s1[3]-nb));
    const float sacc =
        ((__uint_as_float(u0) + __uint_as_float(u1)) +
         (__uint_as_float(u2) + __uint_as_float(u3))) +
        ((__uint_as_float(w0) + __uint_as_float(w1)) +
         (__uint_as_float(w2) + __uint_as_float(w3)));
    sm = fmaf(sm, f, sacc);
    O *= f;
    // packed C-frag dwords: c0,c1 = l-tile0 rows(4g..4g+3); c2,c3 = l-tile1
    const int c0 = (int)pk2(u0, u1), c1 = (int)pk2(u2, u3);
    const int c2 = (int)pk2(w0, w1), c3 = (int)pk2(w2, w3);
    // B-frag dword d of lane(g,m) = l-pair (8g+2d, 8g+2d+1) of column m
    const int p00 = BPERM(aLo, c0), p02 = BPERM(aLo, c2);
    const int p10 = BPERM(aLo, c1), p12 = BPERM(aLo, c3);
    const int p20 = BPERM(aHi, c0), p22 = BPERM(aHi, c2);
    const int p30 = BPERM(aHi, c1), p32 = BPERM(aHi, c3);
    i32x4 bi = { up ? p00 : p02, up ? p10 : p12,
                 up ? p20 : p22, up ? p30 : p32 };
    O = MFMA(aV, __builtin_bit_cast(bf16x8, bi), O, 0, 0, 0);
}

__global__ __launch_bounds__(256)
void attn_mfma(const unsigned short* __restrict__ qb,
               const unsigned short* __restrict__ kb,
               const unsigned short* __restrict__ vb,
               float* __restrict__ head)
{
    const int hb   = blockIdx.x >> 2;
    const int mc   = blockIdx.x & 3;
    const int tid  = threadIdx.x;
    const int wave = tid >> 6;
    const int lane = tid & 63;
    const int g    = lane >> 4;
    const int mR   = lane & 15;
    const int mb   = mc * 128 + wave * 32;

    // K B-frags, register-resident (normal + hi/lo-swapped halves)
    const unsigned short* Kr0 = kb + ((size_t)hb * LL + mb + mR) * 32;
    const unsigned short* Kr1 = Kr0 + 16 * 32;
    const bf16x8 bK0  = *(const bf16x8*)(Kr0 + g * 8);
    const bf16x8 bK0s = *(const bf16x8*)(Kr0 + (g ^ 2) * 8);
    const bf16x8 bK1  = *(const bf16x8*)(Kr1 + g * 8);
    const bf16x8 bK1s = *(const bf16x8*)(Kr1 + (g ^ 2) * 8);

    // A-fragment row = mR (lane&15); k-offset = g*8 within the split row
    const unsigned short* qrow =
        qb + ((size_t)hb * LL + mR) * 32 + g * 8;
    const unsigned short* vrow = vb + ((size_t)hb * DK + mR) * LL + g * 8;

    f32x4 O0 = {0.f,0.f,0.f,0.f}, O1 = {0.f,0.f,0.f,0.f};
    float bar0 = -1e30f, bar1 = -1e30f, sm0 = 0.f, sm1 = 0.f;

    // bpermute byte-addresses: source lanes (s0,m),(s0+1,m), s0=(g&1)*2
    const int aLo = ((g & 1) * 32 + mR) * 4;
    const int aHi = aLo + 64;
    const bool up = (g < 2);

    for (int l = 0; l < LL; l += 32) {
        const bf16x8 aQ0 = *(const bf16x8*)(qrow + (size_t)l * 32);
        const bf16x8 aQ1 = *(const bf16x8*)(qrow + (size_t)(l + 16) * 32);

        const f32x4 z = {0.f,0.f,0.f,0.f};
        f32x4 sA0 = MFMA(aQ0, bK0, z, 0,0,0);  sA0 = MFMA(aQ0, bK0s, sA0, 0,0,0);
        f32x4 sB0 = MFMA(aQ0, bK1, z, 0,0,0);  sB0 = MFMA(aQ0, bK1s, sB0, 0,0,0);
        f32x4 sA1 = MFMA(aQ1, bK0, z, 0,0,0);  sA1 = MFMA(aQ1, bK0s, sA1, 0,0,0);
        f32x4 sB1 = MFMA(aQ1, bK1, z, 0,0,0);  sB1 = MFMA(aQ1, bK1s, sB1, 0,0,0);

        // per-column (m) tile max over the 32 l's: 4 regs + lanes m,m+16,+32,+48
        float tmA = fmaxf(fmaxf(fmaxf(sA0[0],sA0[1]), fmaxf(sA0[2],sA0[3])),
                          fmaxf(fmaxf(sA1[0],sA1[1]), fmaxf(sA1[2],sA1[3])));
        float tmB = fmaxf(fmaxf(fmaxf(sB0[0],sB0[1]), fmaxf(sB0[2],sB0[3])),
                          fmaxf(fmaxf(sB1[0],sB1[1]), fmaxf(sB1[2],sB1[3])));
        tmA = fmaxf(tmA, __shfl_xor(tmA, 16, 64));
        tmA = fmaxf(tmA, __shfl_xor(tmA, 32, 64));
        tmB = fmaxf(tmB, __shfl_xor(tmB, 16, 64));
        tmB = fmaxf(tmB, __shfl_xor(tmB, 32, 64));

        // FIX: include unless relative contribution < 2^-32
        // (bar = max_tm + 32, so the cutoff is tm + 64 <= bar, NOT tm + 32)
        if (__any(tmA + 64.f > bar0) || __any(tmB + 64.f > bar1)) {
            const bf16x8 aV = *(const bf16x8*)(vrow + l);
            soft_pv(sA0, sA1, tmA, bar0, sm0, O0, aV, aLo, aHi, up);
            soft_pv(sB0, sB1, tmB, bar1, sm1, O1, aV, aLo, aHi, up);
        }
    }

    // finalize: sum over the 4 lane-groups (each accumulated distinct l's)
    sm0 += __shfl_xor(sm0, 16, 64);  sm0 += __shfl_xor(sm0, 32, 64);
    sm1 += __shfl_xor(sm1, 16, 64);  sm1 += __shfl_xor(sm1, 32, 64);
    const float i0 = 1.f / sm0, i1 = 1.f / sm1;

    const int h = hb / NB, bb = hb % NB;
    float* __restrict__ ho =
        head + (size_t)(bb * DM + h * DK + 4 * g) * LL + mb + mR;
    #pragma unroll
    for (int i = 0; i < 4; ++i) {                   // row v = 4g+i, col m
        ho[(size_t)i * LL]      = O0[i] * i0;
        ho[(size_t)i * LL + 16] = O1[i] * i1;
    }
}

// ---------------------------------------------------------------------------
// Kernel 3: out[b] = Wo[b] @ head[b]. 768 blocks, Wo via s_load (uniform rows).
// ---------------------------------------------------------------------------
__global__ __launch_bounds__(256)
void out_proj(const float* __restrict__ Wo,
              const float* __restrict__ head,
              float* __restrict__ out)
{
    const int blk  = blockIdx.x;
    const int b    = blk >> 5;
    const int rc   = (blk >> 1) & 15;
    const int cc   = blk & 1;
    const int col  = cc * 256 + threadIdx.x;
    const int row0 = rc * 8;                        // blockIdx-only -> uniform

    const float* __restrict__ wo = Wo + (size_t)b * DM * DM + (size_t)row0 * DM;
    const float* __restrict__ hd = head + (size_t)b * DM * LL + col;

    float acc[8];
    #pragma unroll
    for (int i = 0; i < 8; ++i) acc[i] = 0.f;

    #pragma unroll 4
    for (int d = 0; d < DM; ++d) {
        const float hv = hd[(size_t)d * LL];        // coalesced
        #pragma unroll
        for (int i = 0; i < 8; ++i)
            acc[i] = fmaf(wo[i * DM + d], hv, acc[i]);
    }

    float* __restrict__ ob = out + (size_t)b * DM * LL + (size_t)row0 * LL + col;
    #pragma unroll
    for (int i = 0; i < 8; ++i)
        ob[(size_t)i * LL] = acc[i];
}

extern "C" void kernel_launch(void* const* d_in, const int* in_sizes, int n_in,
                              void* d_out, int out_size, void* d_ws, size_t ws_size,
                              hipStream_t stream) {
    const float* x  = (const float*)d_in[0];
    const float* Wq = (const float*)d_in[1];
    const float* Wk = (const float*)d_in[2];
    const float* Wv = (const float*)d_in[3];
    const float* Wo = (const float*)d_in[4];
    float* out = (float*)d_out;

    char* ws = (char*)d_ws;
    unsigned short* qb   = (unsigned short*)(ws + QB_OFF);
    unsigned short* kb   = (unsigned short*)(ws + KB_OFF);
    unsigned short* vb   = (unsigned short*)(ws + VB_OFF);
    float*          head = (float*)(ws + HEAD_OFF);

    qkv_proj <<<HB * 3, 256, 0, stream>>>(x, Wq, Wk, Wv, qb, kb, vb);
    attn_mfma<<<HB * 4, 256, 0, stream>>>(qb, kb, vb, head);
    out_proj <<<NB * 32, 256, 0, stream>>>(Wo, head, out);
}

// Round 10
// 126.864 us; speedup vs baseline: 2.2079x; 1.0504x over previous
//
#include <hip/hip_runtime.h>
#include <math.h>

#define NB 24
#define DM 128
#define NH 8
#define DK 16
#define LL 512
#define HB (NH * NB)   // 192

// ---------------------------------------------------------------------------
// Workspace layout (BYTES), ~31 MB total:
//   xThi/xTlo [NB][LL][DM] ushort : x transposed, split bf16 (B-frag layout)
//   Whi/Wlo   [HB][3][16][128]    : W split bf16 (A-frag layout), idx hb*3+mat
//   Wob       [NB][128][128]      : Wo plain bf16
//   qb/kb     [HB][LL][32]        : split rows, [0:16]=hi(k) [16:32]=lo(k);
//                                   K pre-scaled by 0.25*log2e
//   vb        [HB][DK][LL]        : V plain bf16
//   headT     [NB][LL][DM]        : attention out, bf16, B-frag layout for Wo
// ---------------------------------------------------------------------------
#define XTH_OFF 0
#define XTL_OFF 3145728
#define WHI_OFF 6291456
#define WLO_OFF 8650752
#define WOB_OFF 11010048
#define QB_OFF  11796480
#define KB_OFF  18087936
#define VB_OFF  24379392
#define HT_OFF  27525120

typedef __attribute__((ext_vector_type(8))) short bf16x8;   // 4 VGPR MFMA A/B
typedef __attribute__((ext_vector_type(4))) float f32x4;    // MFMA C/D
typedef __attribute__((ext_vector_type(4))) int   i32x4;

#define MFMA  __builtin_amdgcn_mfma_f32_16x16x32_bf16
#define EXP2  __builtin_amdgcn_exp2f
#define BPERM __builtin_amdgcn_ds_bpermute

// bf16 rounding (round-half-up), result kept in the high half of a uint
static __device__ __forceinline__ unsigned bfr(float x) {
    return (__float_as_uint(x) + 0x8000u) & 0xffff0000u;
}
static __device__ __forceinline__ unsigned pk2(unsigned e, unsigned o) {
    return (e >> 16) | o;
}

// ---------------------------------------------------------------------------
// Kernel 0: prep. 864 blocks:
//   [0,192)   x -> xThi/xTlo  (LDS transpose, +1-pad), b=bid/8 lc=bid%8
//   [192,768) W split, w=bid-192: hb=w/3 mat=w%3
//   [768,864) Wo -> bf16
// ---------------------------------------------------------------------------
__global__ __launch_bounds__(256)
void prep(const float* __restrict__ x,
          const float* __restrict__ Wq,
          const float* __restrict__ Wk,
          const float* __restrict__ Wv,
          const float* __restrict__ Wo,
          unsigned short* __restrict__ xthi,
          unsigned short* __restrict__ xtlo,
          unsigned short* __restrict__ whi,
          unsigned short* __restrict__ wlo,
          unsigned short* __restrict__ wob)
{
    __shared__ float T[128][65];
    const int bid = blockIdx.x, tid = threadIdx.x;

    if (bid < 192) {
        const int b = bid >> 3, lc = bid & 7;
        const float* __restrict__ xb = x + (size_t)b * 65536 + lc * 64;
        #pragma unroll
        for (int i = 0; i < 32; ++i) {                // coalesced 64-float runs
            const int idx = i * 256 + tid;
            T[idx >> 6][idx & 63] = xb[(size_t)(idx >> 6) * LL + (idx & 63)];
        }
        __syncthreads();
        #pragma unroll
        for (int i = 0; i < 32; ++i) {                // coalesced along d
            const int idx = i * 256 + tid;
            const int l = idx >> 7, d = idx & 127;
            const float v = T[d][l];                  // pad -> conflict-free
            const unsigned h = bfr(v);
            const size_t o = (size_t)b * 65536 + (size_t)(lc * 64 + l) * DM + d;
            xthi[o] = (unsigned short)(h >> 16);
            xtlo[o] = (unsigned short)(bfr(v - __uint_as_float(h)) >> 16);
        }
    } else if (bid < 768) {
        const int w = bid - 192, hb = w / 3, mat = w - hb * 3;
        const float* __restrict__ src =
            (mat == 0 ? Wq : (mat == 1 ? Wk : Wv)) + (size_t)hb * 2048;
        unsigned short* __restrict__ dh = whi + (size_t)w * 2048;
        unsigned short* __restrict__ dl = wlo + (size_t)w * 2048;
        for (int i = tid; i < 2048; i += 256) {
            const float v = src[i];
            const unsigned h = bfr(v);
            dh[i] = (unsigned short)(h >> 16);
            dl[i] = (unsigned short)(bfr(v - __uint_as_float(h)) >> 16);
        }
    } else {
        const int w = bid - 768;                      // 96 blocks x 4096
        const float* __restrict__ src = Wo + (size_t)w * 4096;
        unsigned short* __restrict__ d = wob + (size_t)w * 4096;
        for (int i = tid; i < 4096; i += 256)
            d[i] = (unsigned short)(bfr(src[i]) >> 16);
    }
}

// ---------------------------------------------------------------------------
// Kernel 1: QKV projection on MFMA. 1152 blocks = (hb*3+mat, nc) x 4 waves;
// wave = 4 n-tiles (64 l). Split product (Whi+Wlo)(xhi+xlo) via 3 MFMAs
// (lo*lo ~2^-16 rel, dropped). Per kstep: 2 A loads + 8 B loads + 12 MFMA.
// C emitted straight into the attention layouts (8 B ushort4 stores).
// ---------------------------------------------------------------------------
__global__ __launch_bounds__(256)
void qkv_mfma(const unsigned short* __restrict__ xthi,
              const unsigned short* __restrict__ xtlo,
              const unsigned short* __restrict__ whi,
              const unsigned short* __restrict__ wlo,
              unsigned short* __restrict__ qb,
              unsigned short* __restrict__ kb,
              unsigned short* __restrict__ vb)
{
    const int blk  = blockIdx.x;
    const int nc   = blk & 1;
    const int hm   = blk >> 1;        // hb*3 + mat
    const int mat  = hm % 3;
    const int hb   = hm / 3;
    const int b    = hb % NB;
    const int wv   = threadIdx.x >> 6;
    const int lane = threadIdx.x & 63;
    const int g = lane >> 4, mR = lane & 15;
    const int l0 = nc * 256 + wv * 64;

    const unsigned short* __restrict__ wA = whi + (size_t)hm * 2048 + mR * 128 + g * 8;
    const unsigned short* __restrict__ wB = wlo + (size_t)hm * 2048 + mR * 128 + g * 8;
    const unsigned short* __restrict__ xh = xthi + (size_t)b * 65536 + g * 8;
    const unsigned short* __restrict__ xl = xtlo + (size_t)b * 65536 + g * 8;

    f32x4 C[4];
    #pragma unroll
    for (int t = 0; t < 4; ++t) C[t] = (f32x4){0.f, 0.f, 0.f, 0.f};

    #pragma unroll
    for (int kk = 0; kk < 4; ++kk) {
        const bf16x8 aH = *(const bf16x8*)(wA + kk * 32);
        const bf16x8 aL = *(const bf16x8*)(wB + kk * 32);
        #pragma unroll
        for (int t = 0; t < 4; ++t) {
            const size_t lo_ = (size_t)(l0 + t * 16 + mR) * DM + kk * 32;
            const bf16x8 bH = *(const bf16x8*)(xh + lo_);
            const bf16x8 bL = *(const bf16x8*)(xl + lo_);
            C[t] = MFMA(aH, bH, C[t], 0, 0, 0);
            C[t] = MFMA(aH, bL, C[t], 0, 0, 0);
            C[t] = MFMA(aL, bH, C[t], 0, 0, 0);
        }
    }

    if (mat == 2) {                                   // V -> [hb][v][l] bf16
        unsigned short* __restrict__ vo = vb + (size_t)hb * 8192;
        #pragma unroll
        for (int t = 0; t < 4; ++t) {
            const int l = l0 + t * 16 + mR;
            #pragma unroll
            for (int i = 0; i < 4; ++i)
                vo[(size_t)(4 * g + i) * LL + l] =
                    (unsigned short)(bfr(C[t][i]) >> 16);
        }
    } else {                                          // Q/K -> split rows
        const float scale = (mat == 1) ? (0.25f * 1.44269504f) : 1.0f;
        unsigned short* __restrict__ dst =
            (mat == 0 ? qb : kb) + (size_t)hb * LL * 32;
        #pragma unroll
        for (int t = 0; t < 4; ++t) {
            const int l = l0 + t * 16 + mR;
            ushort4 hi4, lo4;
            #pragma unroll
            for (int i = 0; i < 4; ++i) {
                const float v = C[t][i] * scale;
                const unsigned h = bfr(v);
                const unsigned lw = bfr(v - __uint_as_float(h));
                ((unsigned short*)&hi4)[i] = (unsigned short)(h >> 16);
                ((unsigned short*)&lo4)[i] = (unsigned short)(lw >> 16);
            }
            *(ushort4*)(dst + (size_t)l * 32 + 4 * g)      = hi4;
            *(ushort4*)(dst + (size_t)l * 32 + 16 + 4 * g) = lo4;
        }
    }
}

// ---------------------------------------------------------------------------
// Kernel 2: MFMA flash attention (softmax over l = query axis). Validated in
// round 9; only change: emits bf16 headT[b][l][d] (B-frag layout for out_mfma)
// instead of fp32 head.
// ---------------------------------------------------------------------------
static __device__ __forceinline__ void soft_pv(
    const f32x4& s0, const f32x4& s1, float tm, float& bar, float& sm,
    f32x4& O, const bf16x8& aV, int aLo, int aHi, bool up)
{
    const float nb = fmaxf(bar, tm + 32.f);
    const float f  = EXP2(bar - nb);
    bar = nb;
    const unsigned u0 = bfr(EXP2(s0[0]-nb)), u1 = bfr(EXP2(s0[1]-nb));
    const unsigned u2 = bfr(EXP2(s0[2]-nb)), u3 = bfr(EXP2(s0[3]-nb));
    const unsigned w0 = bfr(EXP2(s1[0]-nb)), w1 = bfr(EXP2(s1[1]-nb));
    const unsigned w2 = bfr(EXP2(s1[2]-nb)), w3 = bfr(EXP2(s1[3]-nb));
    const float sacc =
        ((__uint_as_float(u0) + __uint_as_float(u1)) +
         (__uint_as_float(u2) + __uint_as_float(u3))) +
        ((__uint_as_float(w0) + __uint_as_float(w1)) +
         (__uint_as_float(w2) + __uint_as_float(w3)));
    sm = fmaf(sm, f, sacc);
    O *= f;
    const int c0 = (int)pk2(u0, u1), c1 = (int)pk2(u2, u3);
    const int c2 = (int)pk2(w0, w1), c3 = (int)pk2(w2, w3);
    const int p00 = BPERM(aLo, c0), p02 = BPERM(aLo, c2);
    const int p10 = BPERM(aLo, c1), p12 = BPERM(aLo, c3);
    const int p20 = BPERM(aHi, c0), p22 = BPERM(aHi, c2);
    const int p30 = BPERM(aHi, c1), p32 = BPERM(aHi, c3);
    i32x4 bi = { up ? p00 : p02, up ? p10 : p12,
                 up ? p20 : p22, up ? p30 : p32 };
    O = MFMA(aV, __builtin_bit_cast(bf16x8, bi), O, 0, 0, 0);
}

__global__ __launch_bounds__(256)
void attn_mfma(const unsigned short* __restrict__ qb,
               const unsigned short* __restrict__ kb,
               const unsigned short* __restrict__ vb,
               unsigned short* __restrict__ ht)
{
    const int hb   = blockIdx.x >> 2;
    const int mc   = blockIdx.x & 3;
    const int tid  = threadIdx.x;
    const int wave = tid >> 6;
    const int lane = tid & 63;
    const int g    = lane >> 4;
    const int mR   = lane & 15;
    const int mb   = mc * 128 + wave * 32;

    const unsigned short* Kr0 = kb + ((size_t)hb * LL + mb + mR) * 32;
    const unsigned short* Kr1 = Kr0 + 16 * 32;
    const bf16x8 bK0  = *(const bf16x8*)(Kr0 + g * 8);
    const bf16x8 bK0s = *(const bf16x8*)(Kr0 + (g ^ 2) * 8);
    const bf16x8 bK1  = *(const bf16x8*)(Kr1 + g * 8);
    const bf16x8 bK1s = *(const bf16x8*)(Kr1 + (g ^ 2) * 8);

    const unsigned short* qrow = qb + ((size_t)hb * LL + mR) * 32 + g * 8;
    const unsigned short* vrow = vb + ((size_t)hb * DK + mR) * LL + g * 8;

    f32x4 O0 = {0.f,0.f,0.f,0.f}, O1 = {0.f,0.f,0.f,0.f};
    float bar0 = -1e30f, bar1 = -1e30f, sm0 = 0.f, sm1 = 0.f;

    const int aLo = ((g & 1) * 32 + mR) * 4;
    const int aHi = aLo + 64;
    const bool up = (g < 2);

    for (int l = 0; l < LL; l += 32) {
        const bf16x8 aQ0 = *(const bf16x8*)(qrow + (size_t)l * 32);
        const bf16x8 aQ1 = *(const bf16x8*)(qrow + (size_t)(l + 16) * 32);

        const f32x4 z = {0.f,0.f,0.f,0.f};
        f32x4 sA0 = MFMA(aQ0, bK0, z, 0,0,0);  sA0 = MFMA(aQ0, bK0s, sA0, 0,0,0);
        f32x4 sB0 = MFMA(aQ0, bK1, z, 0,0,0);  sB0 = MFMA(aQ0, bK1s, sB0, 0,0,0);
        f32x4 sA1 = MFMA(aQ1, bK0, z, 0,0,0);  sA1 = MFMA(aQ1, bK0s, sA1, 0,0,0);
        f32x4 sB1 = MFMA(aQ1, bK1, z, 0,0,0);  sB1 = MFMA(aQ1, bK1s, sB1, 0,0,0);

        float tmA = fmaxf(fmaxf(fmaxf(sA0[0],sA0[1]), fmaxf(sA0[2],sA0[3])),
                          fmaxf(fmaxf(sA1[0],sA1[1]), fmaxf(sA1[2],sA1[3])));
        float tmB = fmaxf(fmaxf(fmaxf(sB0[0],sB0[1]), fmaxf(sB0[2],sB0[3])),
                          fmaxf(fmaxf(sB1[0],sB1[1]), fmaxf(sB1[2],sB1[3])));
        tmA = fmaxf(tmA, __shfl_xor(tmA, 16, 64));
        tmA = fmaxf(tmA, __shfl_xor(tmA, 32, 64));
        tmB = fmaxf(tmB, __shfl_xor(tmB, 16, 64));
        tmB = fmaxf(tmB, __shfl_xor(tmB, 32, 64));

        if (__any(tmA + 64.f > bar0) || __any(tmB + 64.f > bar1)) {
            const bf16x8 aV = *(const bf16x8*)(vrow + l);
            soft_pv(sA0, sA1, tmA, bar0, sm0, O0, aV, aLo, aHi, up);
            soft_pv(sB0, sB1, tmB, bar1, sm1, O1, aV, aLo, aHi, up);
        }
    }

    sm0 += __shfl_xor(sm0, 16, 64);  sm0 += __shfl_xor(sm0, 32, 64);
    sm1 += __shfl_xor(sm1, 16, 64);  sm1 += __shfl_xor(sm1, 32, 64);
    const float i0 = 1.f / sm0, i1 = 1.f / sm1;

    const int h = hb / NB, bb = hb % NB;
    // headT[b][l][d]: lane writes d = h*16+4g..+3 at l = mb+mR (and +16)
    unsigned short* __restrict__ ho =
        ht + (size_t)bb * 65536 + (size_t)(mb + mR) * DM + h * 16 + 4 * g;
    ushort4 p0, p1;
    #pragma unroll
    for (int i = 0; i < 4; ++i) {
        ((unsigned short*)&p0)[i] = (unsigned short)(bfr(O0[i] * i0) >> 16);
        ((unsigned short*)&p1)[i] = (unsigned short)(bfr(O1[i] * i1) >> 16);
    }
    *(ushort4*)ho              = p0;
    *(ushort4*)(ho + 16 * DM)  = p1;
}

// ---------------------------------------------------------------------------
// Kernel 3: out = Wo @ headT on MFMA. 768 blocks = (b, mq 2, nq 16) x 4 waves;
// wave = m-tile (mq*4+w), 2 n-tiles. Per kstep: 1 A + 2 B loads + 2 MFMA.
// ---------------------------------------------------------------------------
__global__ __launch_bounds__(256)
void out_mfma(const unsigned short* __restrict__ wob,
              const unsigned short* __restrict__ ht,
              float* __restrict__ out)
{
    const int blk  = blockIdx.x;
    const int b    = blk >> 5;
    const int mq   = (blk >> 4) & 1;
    const int nq   = blk & 15;
    const int wv   = threadIdx.x >> 6;
    const int lane = threadIdx.x & 63;
    const int g = lane >> 4, mR = lane & 15;
    const int m0 = (mq * 4 + wv) * 16;
    const int n0 = nq * 32;

    const unsigned short* __restrict__ A =
        wob + (size_t)b * 16384 + (size_t)(m0 + mR) * DM + g * 8;
    const unsigned short* __restrict__ B = ht + (size_t)b * 65536 + g * 8;

    f32x4 C0 = {0.f,0.f,0.f,0.f}, C1 = {0.f,0.f,0.f,0.f};
    #pragma unroll
    for (int kk = 0; kk < 4; ++kk) {
        const bf16x8 aW = *(const bf16x8*)(A + kk * 32);
        const bf16x8 b0 = *(const bf16x8*)(B + (size_t)(n0 + mR) * DM + kk * 32);
        const bf16x8 b1 = *(const bf16x8*)(B + (size_t)(n0 + 16 + mR) * DM + kk * 32);
        C0 = MFMA(aW, b0, C0, 0, 0, 0);
        C1 = MFMA(aW, b1, C1, 0, 0, 0);
    }

    float* __restrict__ ob = out + (size_t)b * 65536 + (size_t)(m0 + 4 * g) * LL;
    #pragma unroll
    for (int i = 0; i < 4; ++i) {
        ob[(size_t)i * LL + n0 + mR]      = C0[i];
        ob[(size_t)i * LL + n0 + 16 + mR] = C1[i];
    }
}

extern "C" void kernel_launch(void* const* d_in, const int* in_sizes, int n_in,
                              void* d_out, int out_size, void* d_ws, size_t ws_size,
                              hipStream_t stream) {
    const float* x  = (const float*)d_in[0];
    const float* Wq = (const float*)d_in[1];
    const float* Wk = (const float*)d_in[2];
    const float* Wv = (const float*)d_in[3];
    const float* Wo = (const float*)d_in[4];
    float* out = (float*)d_out;

    char* ws = (char*)d_ws;
    unsigned short* xthi = (unsigned short*)(ws + XTH_OFF);
    unsigned short* xtlo = (unsigned short*)(ws + XTL_OFF);
    unsigned short* whi  = (unsigned short*)(ws + WHI_OFF);
    unsigned short* wlo  = (unsigned short*)(ws + WLO_OFF);
    unsigned short* wob  = (unsigned short*)(ws + WOB_OFF);
    unsigned short* qb   = (unsigned short*)(ws + QB_OFF);
    unsigned short* kb   = (unsigned short*)(ws + KB_OFF);
    unsigned short* vb   = (unsigned short*)(ws + VB_OFF);
    unsigned short* ht   = (unsigned short*)(ws + HT_OFF);

    prep     <<<864,     256, 0, stream>>>(x, Wq, Wk, Wv, Wo, xthi, xtlo, whi, wlo, wob);
    qkv_mfma <<<HB * 6,  256, 0, stream>>>(xthi, xtlo, whi, wlo, qb, kb, vb);
    attn_mfma<<<HB * 4,  256, 0, stream>>>(qb, kb, vb, ht);
    out_mfma <<<NB * 32, 256, 0, stream>>>(wob, ht, out);
}